// Round 12
// baseline (67.636 us; speedup 1.0000x reference)
//
#include <hip/hip_runtime.h>
#include <hip/hip_bf16.h>

#define SDIM 4096
#define DDIM 64
#define HN   16
#define BH   64
#define NC   16

typedef __attribute__((ext_vector_type(8))) short short8;
typedef __attribute__((ext_vector_type(4))) float f32x4;

static __device__ __forceinline__ unsigned f2bfu(float f) {
    __hip_bfloat16 h = __float2bfloat16(f);      // HW RNE cvt (pk-fusable)
    return (unsigned)*reinterpret_cast<unsigned short*>(&h);
}
static __device__ __forceinline__ short f2bfs(float f) {
    __hip_bfloat16 h = __float2bfloat16(f);
    return *reinterpret_cast<short*>(&h);
}

#define KTPITCH 136   // bytes per d-row of 64 bf16 s-values (+8 pad: bank spread)

// ---------------------------------------------------------------------------
// k1 v9: per (bh, 256-row chunk) partial KV[64][64] + ksum[64].
//  - k3-style streaming: coalesced dwordx4 row loads, next tile's loads
//    issued BEFORE current tile's compute (latency hidden, no async/races).
//  - relu+mask+bf16 cvt ONCE per element in regs; s-pairs packed via
//    shfl_xor(16); written transposed to K^T/V^T LDS [64d][pitch 136B]
//    (pitch-136 spreads rows across banks: writes ~4-way, reads ~2-4-way).
//  - Fragments = 2x ds_read_b64 per row (8 consecutive s per lane) feeding
//    the validated mfma_16x16x32 layout. Double-buffered, 1 syncthreads/tile.
//  - ksum in fp32 at cvt time + shfl/LDS reduce. Writeout = validated bounce.
// ---------------------------------------------------------------------------
__global__ __launch_bounds__(256, 4) void k1_kv(
    const float* __restrict__ K, const float* __restrict__ V,
    const int* __restrict__ mask,
    float* __restrict__ KVp, float* __restrict__ ksump)
{
    __shared__ __align__(16) char smem[35840];
    char* const KT0 = smem;                 // [64][136]
    char* const VT0 = smem + 8704;
    char* const KT1 = smem + 17408;
    char* const VT1 = smem + 26112;
    float* const kswork = (float*)(smem + 34816);   // 256 f32

    const int tid = threadIdx.x;
    const int w = tid >> 6, l = tid & 63;
    const int a = l & 15, quad = l >> 4;
    const int bh = blockIdx.x >> 4, ch = blockIdx.x & 15;
    const int b  = bh >> 4;                 // bh / HN
    const long base = (long)bh * SDIM * DDIM;
    const int s0 = ch * 256;

    const int rb  = tid >> 4;               // base row 0..15
    const int c4  = (tid & 15) << 2;        // d-base 0..60
    const int par = rb & 1;                 // partner parity (xor 16)

    f32x4 acc[4];
#pragma unroll
    for (int i = 0; i < 4; ++i) acc[i] = (f32x4){0.f, 0.f, 0.f, 0.f};
    float ks4[4] = {0.f, 0.f, 0.f, 0.f};

    f32x4 kr[4], vr[4];
    float mr[4];
#pragma unroll
    for (int i = 0; i < 4; ++i) {           // prefetch tile 0
        const int row = rb + 16 * i;
        kr[i] = *(const f32x4*)(K + base + (long)(s0 + row) * DDIM + c4);
        vr[i] = *(const f32x4*)(V + base + (long)(s0 + row) * DDIM + c4);
        mr[i] = mask[b * SDIM + s0 + row] ? 1.f : 0.f;
    }

    for (int t = 0; t < 4; ++t) {           // 4 tiles of 64 s-rows
        char* const KT = (t & 1) ? KT1 : KT0;
        char* const VT = (t & 1) ? VT1 : VT0;

        // ---- cvt + transpose-pack + LDS write (tile t) ----
#pragma unroll
        for (int i = 0; i < 4; ++i) {
            const int row = rb + 16 * i;
            const int sp  = row >> 1;       // s-pair index
            float kq[4], vq[4];
            kq[0] = fmaxf(kr[i].x, 0.f) * mr[i];
            kq[1] = fmaxf(kr[i].y, 0.f) * mr[i];
            kq[2] = fmaxf(kr[i].z, 0.f) * mr[i];
            kq[3] = fmaxf(kr[i].w, 0.f) * mr[i];
            vq[0] = vr[i].x; vq[1] = vr[i].y; vq[2] = vr[i].z; vq[3] = vr[i].w;
#pragma unroll
            for (int j = 0; j < 4; ++j) ks4[j] += kq[j];
            unsigned ku[4], vu[4];
#pragma unroll
            for (int j = 0; j < 4; ++j) {
                ku[j] = f2bfu(kq[j]);
                vu[j] = f2bfu(vq[j]);
            }
            unsigned kp32[4], vp32[4];
#pragma unroll
            for (int j = 0; j < 4; ++j) {
                const unsigned pk = (unsigned)__shfl_xor((int)ku[j], 16);
                const unsigned pv = (unsigned)__shfl_xor((int)vu[j], 16);
                kp32[j] = par ? (pk | (ku[j] << 16)) : (ku[j] | (pk << 16));
                vp32[j] = par ? (pv | (vu[j] << 16)) : (vu[j] | (pv << 16));
            }
            const int j0 = par * 2;         // even rows write j 0,1; odd 2,3
            *(unsigned*)(KT + (c4 + j0)     * KTPITCH + sp * 4) = kp32[j0];
            *(unsigned*)(KT + (c4 + j0 + 1) * KTPITCH + sp * 4) = kp32[j0 + 1];
            *(unsigned*)(VT + (c4 + j0)     * KTPITCH + sp * 4) = vp32[j0];
            *(unsigned*)(VT + (c4 + j0 + 1) * KTPITCH + sp * 4) = vp32[j0 + 1];
        }

        if (t < 3) {                        // issue tile t+1 loads (overlap)
            const int r0n = s0 + (t + 1) * 64;
#pragma unroll
            for (int i = 0; i < 4; ++i) {
                const int row = rb + 16 * i;
                kr[i] = *(const f32x4*)(K + base + (long)(r0n + row) * DDIM + c4);
                vr[i] = *(const f32x4*)(V + base + (long)(r0n + row) * DDIM + c4);
                mr[i] = mask[b * SDIM + r0n + row] ? 1.f : 0.f;
            }
        }

        __syncthreads();                    // tile t staged (1 barrier/tile)

        // ---- compute tile t: 2 k-halves of 32 s ----
#pragma unroll
        for (int kh = 0; kh < 2; ++kh) {
            const int sof = kh * 64 + quad * 16;   // byte offset of 8 s
            short8 af[4];
#pragma unroll
            for (int dt = 0; dt < 4; ++dt) {
                const char* rp = KT + (dt * 16 + a) * KTPITCH + sof;
                const uint2 lo = *(const uint2*)rp;
                const uint2 hi = *(const uint2*)(rp + 8);
                int4 ra; ra.x = lo.x; ra.y = lo.y; ra.z = hi.x; ra.w = hi.y;
                af[dt] = *(short8*)&ra;
            }
            const char* vp = VT + (w * 16 + a) * KTPITCH + sof;
            const uint2 vlo = *(const uint2*)vp;
            const uint2 vhi = *(const uint2*)(vp + 8);
            int4 rb4; rb4.x = vlo.x; rb4.y = vlo.y; rb4.z = vhi.x; rb4.w = vhi.y;
            const short8 bf = *(short8*)&rb4;
#pragma unroll
            for (int dt = 0; dt < 4; ++dt)
                acc[dt] = __builtin_amdgcn_mfma_f32_16x16x32_bf16(
                    af[dt], bf, acc[dt], 0, 0, 0);
        }
    }

    // ---- ksum reduce: threads sharing c4 are lanes {c,c+16,c+32,c+48} ----
#pragma unroll
    for (int j = 0; j < 4; ++j) {
        ks4[j] += __shfl_xor(ks4[j], 16);
        ks4[j] += __shfl_xor(ks4[j], 32);
    }
    __syncthreads();                        // staging LDS now dead
    float* const kb = (float*)smem;         // 16 KB bounce (offset 0)
#pragma unroll
    for (int dt = 0; dt < 4; ++dt)
#pragma unroll
        for (int r = 0; r < 4; ++r) {
            const int d = dt * 16 + quad * 4 + r;
            const int e = w * 16 + a;
            kb[d * 64 + (e ^ (((d >> 3) & 3) << 4))] = acc[dt][r];
        }
    if (l < 16) {
#pragma unroll
        for (int j = 0; j < 4; ++j) kswork[w * 64 + l * 4 + j] = ks4[j];
    }
    __syncthreads();
    float* outp = KVp + ((long)bh * NC + ch) * 4096;
#pragma unroll
    for (int i = 0; i < 16; ++i) {
        const int idx = i * 256 + tid;
        const int d = idx >> 6, e = idx & 63;
        outp[idx] = kb[d * 64 + (e ^ (((d >> 3) & 3) << 4))];
    }
    if (tid < 64)
        ksump[((long)bh * NC + ch) * 64 + tid] =
            kswork[tid] + kswork[64 + tid] + kswork[128 + tid] + kswork[192 + tid];
}

// ---------------------------------------------------------------------------
// k2: reduce NC chunk partials -> final KV, ksum. (unchanged, validated)
// ---------------------------------------------------------------------------
__global__ __launch_bounds__(256) void k2_reduce(
    const float* __restrict__ KVp, const float* __restrict__ ksump,
    float* __restrict__ KV, float* __restrict__ ksum)
{
    const int bh = blockIdx.x >> 2;
    const int qt = blockIdx.x & 3;
    const int tid = threadIdx.x;
#pragma unroll
    for (int i = 0; i < 4; ++i) {
        const int idx = qt * 1024 + i * 256 + tid;
        float v = 0.f;
#pragma unroll
        for (int c = 0; c < NC; ++c) v += KVp[((long)bh * NC + c) * 4096 + idx];
        KV[(long)bh * 4096 + idx] = v;
    }
    if (qt == 0 && tid < 64) {
        float v = 0.f;
#pragma unroll
        for (int c = 0; c < NC; ++c) v += ksump[((long)bh * NC + c) * 64 + tid];
        ksum[bh * 64 + tid] = v;
    }
}

// ---------------------------------------------------------------------------
// k3 v4 (MFMA): out = (relu(Q) @ KV_bf16) * (1/norm), norm fp32.
// (unchanged, validated)
// ---------------------------------------------------------------------------
__global__ __launch_bounds__(256, 4) void k3_out(
    const float* __restrict__ Q, const float* __restrict__ KVm,
    const float* __restrict__ ksum, float* __restrict__ out)
{
    __shared__ float cbuf[4][16 * 68];     // 17.4 KB, per-wave strips
    const int tid  = threadIdx.x;
    const int w    = tid >> 6;
    const int l    = tid & 63;
    const int r16  = l & 15;
    const int quad = l >> 4;
    const int bh    = blockIdx.x >> 4;
    const int strip = blockIdx.x & 15;     // 16 strips x 256 rows

    const float* kvp = KVm + (long)bh * 4096;
    short8 bfrag[2][4];
#pragma unroll
    for (int kh = 0; kh < 2; ++kh)
#pragma unroll
        for (int n = 0; n < 4; ++n) {
            short8 tmp;
#pragma unroll
            for (int j = 0; j < 8; ++j)
                tmp[j] = f2bfs(kvp[(kh * 32 + quad * 8 + j) * 64 + n * 16 + r16]);
            bfrag[kh][n] = tmp;
        }
    float ksv[16];
#pragma unroll
    for (int j = 0; j < 8; ++j) {
        ksv[j]     = ksum[bh * 64 + quad * 8 + j];
        ksv[j + 8] = ksum[bh * 64 + 32 + quad * 8 + j];
    }

    const int rowbase = strip * 256 + w * 64;
    const float* qptr = Q + ((long)bh * SDIM + rowbase + r16) * DDIM + quad * 8;
    float* obase = out + ((long)bh * SDIM + rowbase) * DDIM;
    float* cw = &cbuf[w][0];

    f32x4 a0 = *(const f32x4*)(qptr);
    f32x4 a1 = *(const f32x4*)(qptr + 4);
    f32x4 a2 = *(const f32x4*)(qptr + 32);
    f32x4 a3 = *(const f32x4*)(qptr + 36);

    for (int t = 0; t < 4; ++t) {
        f32x4 b0 = a0, b1 = a1, b2 = a2, b3 = a3;
        if (t < 3) {
            const float* qn = qptr + (t + 1) * 16 * DDIM;
            b0 = *(const f32x4*)(qn);
            b1 = *(const f32x4*)(qn + 4);
            b2 = *(const f32x4*)(qn + 32);
            b3 = *(const f32x4*)(qn + 36);
        }
#pragma unroll
        for (int j = 0; j < 4; ++j) {
            a0[j] = fmaxf(a0[j], 0.f); a1[j] = fmaxf(a1[j], 0.f);
            a2[j] = fmaxf(a2[j], 0.f); a3[j] = fmaxf(a3[j], 0.f);
        }
        float p = 0.f;
#pragma unroll
        for (int j = 0; j < 4; ++j) {
            p = fmaf(a0[j], ksv[j],      p);
            p = fmaf(a1[j], ksv[4 + j],  p);
            p = fmaf(a2[j], ksv[8 + j],  p);
            p = fmaf(a3[j], ksv[12 + j], p);
        }
        p += __shfl_xor(p, 16);
        p += __shfl_xor(p, 32);
        const float inv = __builtin_amdgcn_rcpf(p);

        short8 af0, af1;
#pragma unroll
        for (int j = 0; j < 4; ++j) {
            af0[j]     = f2bfs(a0[j]);
            af0[4 + j] = f2bfs(a1[j]);
            af1[j]     = f2bfs(a2[j]);
            af1[4 + j] = f2bfs(a3[j]);
        }

        f32x4 acc[4];
#pragma unroll
        for (int n = 0; n < 4; ++n) {
            acc[n] = (f32x4){0.f, 0.f, 0.f, 0.f};
            acc[n] = __builtin_amdgcn_mfma_f32_16x16x32_bf16(af0, bfrag[0][n], acc[n], 0, 0, 0);
            acc[n] = __builtin_amdgcn_mfma_f32_16x16x32_bf16(af1, bfrag[1][n], acc[n], 0, 0, 0);
        }

        float invr[4];
#pragma unroll
        for (int r = 0; r < 4; ++r) invr[r] = __shfl(inv, quad * 4 + r);

#pragma unroll
        for (int n = 0; n < 4; ++n)
#pragma unroll
            for (int r = 0; r < 4; ++r)
                cw[(quad * 4 + r) * 68 + n * 16 + r16] = acc[n][r] * invr[r];

        float* ot = obase + (t * 16) * DDIM;
#pragma unroll
        for (int i = 0; i < 4; ++i) {
            f32x4 v = *(const f32x4*)(cw + (i * 4 + quad) * 68 + r16 * 4);
            *(f32x4*)(ot + (i * 4 + quad) * DDIM + r16 * 4) = v;
        }
        a0 = b0; a1 = b1; a2 = b2; a3 = b3;
    }
}

extern "C" void kernel_launch(void* const* d_in, const int* in_sizes, int n_in,
                              void* d_out, int out_size, void* d_ws, size_t ws_size,
                              hipStream_t stream)
{
    const float* Q    = (const float*)d_in[0];
    const float* K    = (const float*)d_in[1];
    const float* V    = (const float*)d_in[2];
    const int*   mask = (const int*)d_in[3];
    float* out = (float*)d_out;

    // Chunk partials live in d_out (scratch; k3 overwrites all of d_out).
    float* KVp   = out;                                // 16.8 MB scratch
    float* ksump = KVp + (long)BH * NC * 4096;         // 256 KB
    float* KV    = (float*)d_ws;                       // 1 MB
    float* ksum  = KV + (long)BH * 4096;               // 16 KB

    hipLaunchKernelGGL(k1_kv, dim3(BH * NC), dim3(256), 0, stream,
                       K, V, mask, KVp, ksump);
    hipLaunchKernelGGL(k2_reduce, dim3(BH * 4), dim3(256), 0, stream,
                       KVp, ksump, KV, ksum);
    hipLaunchKernelGGL(k3_out, dim3(BH * 16), dim3(256), 0, stream,
                       Q, KV, ksum, out);
}